// Round 5
// baseline (251.582 us; speedup 1.0000x reference)
//
#include <hip/hip_runtime.h>

// MHA: B=2, S=2048, D=1024, H=16, DK=64. All GEMMs are x @ W.T (+bias).
// R5 changes:
//  - GEMMs: BK=64 (half the barriers per K-loop; 32KB LDS, occupancy grid-limited).
//  - attn: 128-row Q-tile, wave owns 32 q-rows as 2x16 chunks. kf/bf fragment
//    reads shared across chunks -> LDS-read per MAC drops 1.8x (was the
//    bottleneck pipe: 18 b128/iter vs 77 cyc MFMA). K/V global re-reads halve.

#define S_LEN 2048
#define BATCH 2
#define DM    1024
#define NH    16
#define DKH   64
#define BS    (BATCH * S_LEN)   // 4096 rows

typedef _Float16 f16x8 __attribute__((ext_vector_type(8)));
typedef _Float16 f16x4 __attribute__((ext_vector_type(4)));
typedef _Float16 f16x2 __attribute__((ext_vector_type(2)));
typedef __fp16   h16x2 __attribute__((ext_vector_type(2)));
typedef float    f32x4 __attribute__((ext_vector_type(4)));

__device__ __forceinline__ f16x2 pk_f16(float a, float b) {
  h16x2 r = __builtin_amdgcn_cvt_pkrtz(a, b);
  return __builtin_bit_cast(f16x2, r);
}

__device__ __forceinline__ void gld16(const void* g, void* l) {
  __builtin_amdgcn_global_load_lds(
      (const __attribute__((address_space(1))) void*)g,
      (__attribute__((address_space(3))) void*)l, 16, 0, 0);
}

__device__ __forceinline__ float fast_exp2(float x) {
#if __has_builtin(__builtin_amdgcn_exp2f)
  return __builtin_amdgcn_exp2f(x);
#else
  return exp2f(x);
#endif
}

// ---------------- fp32 -> fp16 conversion ----------------
__global__ __launch_bounds__(256) void cvt_all(
    const float* __restrict__ q, const float* __restrict__ k, const float* __restrict__ v,
    const float* __restrict__ wq, const float* __restrict__ wk,
    const float* __restrict__ wv, const float* __restrict__ wo,
    _Float16* __restrict__ xq, _Float16* __restrict__ xk, _Float16* __restrict__ xv,
    _Float16* __restrict__ w16)
{
  const int y = blockIdx.y;
  const float* src; _Float16* dst; int n;
  if (y == 0)      { src = q;  dst = xq; n = BS * DM; }
  else if (y == 1) { src = k;  dst = xk; n = BS * DM; }
  else if (y == 2) { src = v;  dst = xv; n = BS * DM; }
  else {
    src = (y == 3) ? wq : ((y == 4) ? wk : ((y == 5) ? wv : wo));
    dst = w16 + (size_t)(y - 3) * (DM * DM);
    n = DM * DM;
  }
  int i0 = (blockIdx.x * 256 + threadIdx.x) * 4;
  if (i0 < n) {
    float4 f = *(const float4*)(src + i0);
    f16x2 lo = pk_f16(f.x, f.y);
    f16x2 hi = pk_f16(f.z, f.w);
    f16x4 h; h[0] = lo[0]; h[1] = lo[1]; h[2] = hi[0]; h[3] = hi[1];
    *(f16x4*)(dst + i0) = h;
  }
}

// ---------------- 128x128-tile GEMM: C = (A @ W^T + bias)*oscale ----------------
// BK=64, 16x16x32 MFMA, 4x4 frags/wave, 32 MFMA per barrier pair.
// LDS pitch 64 f16 = 8 16B-blocks/row; phys block = logical ^ (row&7).
template <typename OUT_T>
__device__ __forceinline__ void gemm_core(
    const _Float16* __restrict__ A, const _Float16* __restrict__ W,
    const float* __restrict__ bias, OUT_T* __restrict__ out, float oscale)
{
  const int tid  = threadIdx.x;
  const int l    = tid & 63;
  const int wv   = tid >> 6;
  const int c    = l & 15, quad = l >> 4;
  const int m0   = blockIdx.y * 128, n0 = blockIdx.x * 128;
  const int wm   = wv & 1, wn = wv >> 1;
  __shared__ _Float16 sA[128 * 64];
  __shared__ _Float16 sB[128 * 64];

  // staging: 1024 16B-slots per buffer; thread handles slots tid + p*256.
  // slot s: LDS block s (linear), global row s>>3, gblock (s&7)^((s>>3)&7).
  const _Float16* gA[4]; const _Float16* gB[4];
#pragma unroll
  for (int p = 0; p < 4; ++p) {
    int s = tid + p * 256, r = s >> 3, g = (s & 7) ^ (r & 7);
    gA[p] = A + (size_t)(m0 + r) * DM + g * 8;
    gB[p] = W + (size_t)(n0 + r) * DM + g * 8;
  }
  const int cx = c & 7;   // frag-read block xor (row&7 == c&7 for frag rows)

  f32x4 acc[4][4] = {};
  for (int k0 = 0; k0 < DM; k0 += 64) {
    __syncthreads();
#pragma unroll
    for (int p = 0; p < 4; ++p) {
      gld16(gA[p] + k0, sA + (tid + p * 256) * 8);
      gld16(gB[p] + k0, sB + (tid + p * 256) * 8);
    }
    __syncthreads();   // vmcnt drained -> tile ready
#pragma unroll
    for (int ks = 0; ks < 2; ++ks) {
      f16x8 af[4], bf[4];
#pragma unroll
      for (int i = 0; i < 4; ++i)
        af[i] = *(const f16x8*)&sA[(wm * 64 + i * 16 + c) * 64 + ((ks * 4 + quad) ^ cx) * 8];
#pragma unroll
      for (int j = 0; j < 4; ++j)
        bf[j] = *(const f16x8*)&sB[(wn * 64 + j * 16 + c) * 64 + ((ks * 4 + quad) ^ cx) * 8];
#pragma unroll
      for (int i = 0; i < 4; ++i)
#pragma unroll
        for (int j = 0; j < 4; ++j)
          acc[i][j] = __builtin_amdgcn_mfma_f32_16x16x32_f16(af[i], bf[j], acc[i][j], 0, 0, 0);
    }
  }
#pragma unroll
  for (int j = 0; j < 4; ++j) {
    int col = n0 + wn * 64 + j * 16 + c;
    float bb = bias[col];
#pragma unroll
    for (int i = 0; i < 4; ++i) {
      int row = m0 + wm * 64 + i * 16 + quad * 4;
#pragma unroll
      for (int r = 0; r < 4; ++r) {
        float vv = (acc[i][j][r] + bb) * oscale;
        out[(size_t)(row + r) * DM + col] = (OUT_T)vv;
      }
    }
  }
}

#define SC_Q (0.125f * 1.44269504088896340736f)   // 1/sqrt(64) * log2(e)

__global__ __launch_bounds__(256) void proj3(
    const _Float16* __restrict__ xq, const _Float16* __restrict__ xk,
    const _Float16* __restrict__ xv, const _Float16* __restrict__ w16,
    const float* __restrict__ bq, const float* __restrict__ bk, const float* __restrict__ bv,
    _Float16* __restrict__ Q, _Float16* __restrict__ K, _Float16* __restrict__ V)
{
  const int z = blockIdx.z;
  const _Float16* A    = (z == 0) ? xq : ((z == 1) ? xk : xv);
  const _Float16* W    = w16 + (size_t)z * (DM * DM);
  const float*    bias = (z == 0) ? bq : ((z == 1) ? bk : bv);
  _Float16*       out  = (z == 0) ? Q : ((z == 1) ? K : V);
  const float     os   = (z == 0) ? SC_Q : 1.0f;
  gemm_core<_Float16>(A, W, bias, out, os);
}

__global__ __launch_bounds__(256) void out_gemm(
    const _Float16* __restrict__ ctx, const _Float16* __restrict__ wo,
    const float* __restrict__ bo, float* __restrict__ out)
{
  gemm_core<float>(ctx, wo, bo, out, 1.0f);
}

// ---------------- V transpose: V[b,s,h*64+d] -> Vt[(b,h,d), s] ----------------
__global__ __launch_bounds__(256) void vtrans(const _Float16* __restrict__ V,
                                              _Float16* __restrict__ Vt)
{
  const int tid = threadIdx.x;
  const int s0  = blockIdx.x * 64;
  const int bh  = blockIdx.y;
  const int b   = bh >> 4, h = bh & 15;
  __shared__ _Float16 t[64 * 68];
  const _Float16* Vg = V + ((size_t)(b * S_LEN + s0)) * DM + h * DKH;
#pragma unroll
  for (int p = 0; p < 2; ++p) {
    int cc = tid + p * 256;
    int r = cc >> 3, off = (cc & 7) << 3;
    f16x8 vv = *(const f16x8*)(Vg + (size_t)r * DM + off);
    f16x4 lo, hi;
    lo.x = vv[0]; lo.y = vv[1]; lo.z = vv[2]; lo.w = vv[3];
    hi.x = vv[4]; hi.y = vv[5]; hi.z = vv[6]; hi.w = vv[7];
    *(f16x4*)&t[r * 68 + off]     = lo;
    *(f16x4*)&t[r * 68 + off + 4] = hi;
  }
  __syncthreads();
  const int cpos = tid & 63, dbase = tid >> 6;
  _Float16* Og = Vt + ((size_t)bh * DKH) * S_LEN + s0 + cpos;
#pragma unroll
  for (int i = 0; i < 16; ++i) {
    int d = dbase + i * 4;
    Og[(size_t)d * S_LEN] = t[cpos * 68 + d];
  }
}

// ---------------- fused flash attention ----------------
// grid (S/128, B*H), 4 waves; wave owns 32 q-rows (2x16 chunks). Q pre-scaled
// so P = 2^S. S^T = mfma(kf, qf): lane holds P[q][4 contiguous keys].
// Fixed-shift softmax (scores bounded, exp <= ~512 << fp16 max) is exact.
#define APP 72   // sP pitch: 16B-aligned rows; b64 writes bank-uniform
__global__ __launch_bounds__(256) void attn(
    const _Float16* __restrict__ Q, const _Float16* __restrict__ K,
    const _Float16* __restrict__ Vt, _Float16* __restrict__ ctx)
{
  const int tid = threadIdx.x;
  const int l   = tid & 63, wv = tid >> 6;
  const int c   = l & 15, quad = l >> 4;
  const int q0  = blockIdx.x * 128;
  const int bh  = blockIdx.y;
  const int b   = bh >> 4, h = bh & 15;
  __shared__ _Float16 sK[64 * 64];        // [key][d], swizzled 16B blocks
  __shared__ _Float16 sV[64 * 64];        // [d][key], swizzled 16B blocks
  __shared__ _Float16 sP[4][32 * APP];    // per-wave P[q][key], 32 q-rows

  f16x8 qf[2][2];
#pragma unroll
  for (int qc = 0; qc < 2; ++qc) {
    const _Float16* Qg = Q + ((size_t)(b * S_LEN + q0 + wv * 32 + qc * 16 + c)) * DM + h * DKH;
    qf[qc][0] = *(const f16x8*)(Qg + quad * 8);
    qf[qc][1] = *(const f16x8*)(Qg + 32 + quad * 8);
  }

  f32x4 o[2][4] = {};
  float l_part[2] = {};

  const _Float16* Kg0 = K + ((size_t)b * S_LEN) * DM + h * DKH;
  const _Float16* Vg0 = Vt + ((size_t)bh * DKH) * S_LEN;

  // staging: 512 16B-blocks per tile; thread handles slots {tid, tid+256} for
  // each of sK, sV. slot s -> LDS block s, global row s>>3, block (s&7)^((s>>3)&7).
  const int sa = tid,      ra = sa >> 3, ba = (sa & 7) ^ (ra & 7);
  const int sb = tid + 256, rb = sb >> 3, bb = (sb & 7) ^ (rb & 7);
  const _Float16* gKa = Kg0 + (size_t)ra * DM + ba * 8;
  const _Float16* gKb = Kg0 + (size_t)rb * DM + bb * 8;
  const _Float16* gVa = Vg0 + (size_t)ra * S_LEN + ba * 8;
  const _Float16* gVb = Vg0 + (size_t)rb * S_LEN + bb * 8;
  const int cx = c & 7;   // frag-read block xor

  for (int kt = 0; kt < S_LEN / 64; ++kt) {
    const int k0 = kt * 64;
    __syncthreads();   // prior tile's LDS reads complete
    gld16(gKa + (size_t)k0 * DM, sK + sa * 8);
    gld16(gKb + (size_t)k0 * DM, sK + sb * 8);
    gld16(gVa + k0,              sV + sa * 8);
    gld16(gVb + k0,              sV + sb * 8);
    __syncthreads();   // vmcnt drained -> tiles ready

    // S^T: rows=keys, cols=q. kf shared across both q-chunks.
    f32x4 sAcc[2][4] = {};
#pragma unroll
    for (int ks = 0; ks < 2; ++ks)
#pragma unroll
      for (int nt = 0; nt < 4; ++nt) {
        f16x8 kf = *(const f16x8*)&sK[(nt * 16 + c) * 64 + ((ks * 4 + quad) ^ cx) * 8];
#pragma unroll
        for (int qc = 0; qc < 2; ++qc)
          sAcc[qc][nt] = __builtin_amdgcn_mfma_f32_16x16x32_f16(kf, qf[qc][ks], sAcc[qc][nt], 0, 0, 0);
      }

    // P = 2^S; lane owns q-row qc*16+c, keys nt*16+quad*4+{0..3} -> b64 spills
#pragma unroll
    for (int qc = 0; qc < 2; ++qc)
#pragma unroll
      for (int nt = 0; nt < 4; ++nt) {
        float p0 = fast_exp2(sAcc[qc][nt][0]);
        float p1 = fast_exp2(sAcc[qc][nt][1]);
        float p2 = fast_exp2(sAcc[qc][nt][2]);
        float p3 = fast_exp2(sAcc[qc][nt][3]);
        l_part[qc] += (p0 + p1) + (p2 + p3);
        f16x2 lo = pk_f16(p0, p1);
        f16x2 hi = pk_f16(p2, p3);
        f16x4 pk; pk[0] = lo[0]; pk[1] = lo[1]; pk[2] = hi[0]; pk[3] = hi[1];
        *(f16x4*)&sP[wv][(qc * 16 + c) * APP + nt * 16 + quad * 4] = pk;
      }
    // no barrier: sP per-wave, DS in-order within wave

    // O += P V; bf shared across both q-chunks.
#pragma unroll
    for (int ks = 0; ks < 2; ++ks) {
      f16x8 bf[4];
#pragma unroll
      for (int nt = 0; nt < 4; ++nt)
        bf[nt] = *(const f16x8*)&sV[(nt * 16 + c) * 64 + ((ks * 4 + quad) ^ cx) * 8];
#pragma unroll
      for (int qc = 0; qc < 2; ++qc) {
        f16x8 af = *(const f16x8*)&sP[wv][(qc * 16 + c) * APP + ks * 32 + quad * 8];
#pragma unroll
        for (int nt = 0; nt < 4; ++nt)
          o[qc][nt] = __builtin_amdgcn_mfma_f32_16x16x32_f16(af, bf[nt], o[qc][nt], 0, 0, 0);
      }
    }
  }

  // epilogue: reduce row sums across quads, normalize, store
#pragma unroll
  for (int qc = 0; qc < 2; ++qc) {
    float lp = l_part[qc];
    lp += __shfl_xor(lp, 16);
    lp += __shfl_xor(lp, 32);
    _Float16* Og = ctx + ((size_t)(b * S_LEN + q0 + wv * 32 + qc * 16 + quad * 4)) * DM + h * DKH;
#pragma unroll
    for (int j = 0; j < 4; ++j) {
      float s = __shfl(lp, quad * 4 + j, 64);
      float inv = 1.0f / s;
#pragma unroll
      for (int nt = 0; nt < 4; ++nt)
        Og[(size_t)j * DM + nt * 16 + c] = (_Float16)(o[qc][nt][j] * inv);
    }
  }
}

extern "C" void kernel_launch(void* const* d_in, const int* in_sizes, int n_in,
                              void* d_out, int out_size, void* d_ws, size_t ws_size,
                              hipStream_t stream)
{
  (void)in_sizes; (void)n_in; (void)out_size; (void)ws_size;
  const float* q  = (const float*)d_in[0];
  const float* k  = (const float*)d_in[1];
  const float* v  = (const float*)d_in[2];
  const float* wq = (const float*)d_in[3];
  const float* bq = (const float*)d_in[4];
  const float* wk = (const float*)d_in[5];
  const float* bk = (const float*)d_in[6];
  const float* wv = (const float*)d_in[7];
  const float* bv = (const float*)d_in[8];
  const float* wo = (const float*)d_in[9];
  const float* bo = (const float*)d_in[10];

  char* ws = (char*)d_ws;
  _Float16* XQ  = (_Float16*)(ws);                    // dead after proj3 -> CTX
  _Float16* XK  = (_Float16*)(ws + (8u  << 20));      // dead after proj3 -> VT
  _Float16* XV  = (_Float16*)(ws + (16u << 20));
  _Float16* W16 = (_Float16*)(ws + (24u << 20));      // Wq,Wk,Wv,Wo
  _Float16* Qp  = (_Float16*)(ws + (32u << 20));
  _Float16* Kp  = (_Float16*)(ws + (40u << 20));
  _Float16* Vp  = (_Float16*)(ws + (48u << 20));
  _Float16* VT  = XK;
  _Float16* CTX = XQ;
  float* out = (float*)d_out;

  cvt_all<<<dim3(4096, 7), 256, 0, stream>>>(q, k, v, wq, wk, wv, wo, XQ, XK, XV, W16);
  proj3<<<dim3(8, 32, 3), 256, 0, stream>>>(XQ, XK, XV, W16, bq, bk, bv, Qp, Kp, Vp);
  vtrans<<<dim3(32, 32), 256, 0, stream>>>(Vp, VT);
  attn<<<dim3(16, 32), 256, 0, stream>>>(Qp, Kp, VT, CTX);
  out_gemm<<<dim3(8, 32), 256, 0, stream>>>(CTX, W16 + (size_t)3 * DM * DM, bo, out);
}

// Round 6
// 240.055 us; speedup vs baseline: 1.0480x; 1.0480x over previous
//
#include <hip/hip_runtime.h>

// MHA: B=2, S=2048, D=1024, H=16, DK=64. All GEMMs are x @ W.T (+bias).
// R6 changes:
//  - attn: 64q tile (grid 1024 = 4 blocks/CU) with work-split redesign:
//    S^T splits KEYS across waves (qf persistent in regs -> kf 2 reads/iter,
//    K read once/block); PV splits q x d 2-way each (af 4 + bf 4; P,V read
//    2x/block). DS per wave-iter 240 -> ~140 cyc at restored co-residency.
//    3 barriers/iter (sP is now cross-wave).
//  - vtrans fused into proj3's V epilogue: MFMA C-layout rows are consecutive
//    s at fixed col -> contiguous f16x4 stores into Vt[(b,h,d),s]. One fewer
//    kernel + 16MB traffic.

#define S_LEN 2048
#define BATCH 2
#define DM    1024
#define NH    16
#define DKH   64
#define BS    (BATCH * S_LEN)   // 4096 rows

typedef _Float16 f16x8 __attribute__((ext_vector_type(8)));
typedef _Float16 f16x4 __attribute__((ext_vector_type(4)));
typedef _Float16 f16x2 __attribute__((ext_vector_type(2)));
typedef __fp16   h16x2 __attribute__((ext_vector_type(2)));
typedef float    f32x4 __attribute__((ext_vector_type(4)));

__device__ __forceinline__ f16x2 pk_f16(float a, float b) {
  h16x2 r = __builtin_amdgcn_cvt_pkrtz(a, b);
  return __builtin_bit_cast(f16x2, r);
}

__device__ __forceinline__ void gld16(const void* g, void* l) {
  __builtin_amdgcn_global_load_lds(
      (const __attribute__((address_space(1))) void*)g,
      (__attribute__((address_space(3))) void*)l, 16, 0, 0);
}

__device__ __forceinline__ float fast_exp2(float x) {
#if __has_builtin(__builtin_amdgcn_exp2f)
  return __builtin_amdgcn_exp2f(x);
#else
  return exp2f(x);
#endif
}

// ---------------- fp32 -> fp16 conversion ----------------
__global__ __launch_bounds__(256) void cvt_all(
    const float* __restrict__ q, const float* __restrict__ k, const float* __restrict__ v,
    const float* __restrict__ wq, const float* __restrict__ wk,
    const float* __restrict__ wv, const float* __restrict__ wo,
    _Float16* __restrict__ xq, _Float16* __restrict__ xk, _Float16* __restrict__ xv,
    _Float16* __restrict__ w16)
{
  const int y = blockIdx.y;
  const float* src; _Float16* dst; int n;
  if (y == 0)      { src = q;  dst = xq; n = BS * DM; }
  else if (y == 1) { src = k;  dst = xk; n = BS * DM; }
  else if (y == 2) { src = v;  dst = xv; n = BS * DM; }
  else {
    src = (y == 3) ? wq : ((y == 4) ? wk : ((y == 5) ? wv : wo));
    dst = w16 + (size_t)(y - 3) * (DM * DM);
    n = DM * DM;
  }
  int i0 = (blockIdx.x * 256 + threadIdx.x) * 4;
  if (i0 < n) {
    float4 f = *(const float4*)(src + i0);
    f16x2 lo = pk_f16(f.x, f.y);
    f16x2 hi = pk_f16(f.z, f.w);
    f16x4 h; h[0] = lo[0]; h[1] = lo[1]; h[2] = hi[0]; h[3] = hi[1];
    *(f16x4*)(dst + i0) = h;
  }
}

// ---------------- 128x128-tile GEMM: C = (A @ W^T + bias)*oscale ----------------
// BK=64, 16x16x32 MFMA, 4x4 frags/wave. global_load_lds staging, XOR swizzle.
// VT mode: write transposed into Vt[(b,h,d), s] with contiguous f16x4 stores.
template <typename OUT_T, bool VT>
__device__ __forceinline__ void gemm_core(
    const _Float16* __restrict__ A, const _Float16* __restrict__ W,
    const float* __restrict__ bias, OUT_T* __restrict__ out, float oscale)
{
  const int tid  = threadIdx.x;
  const int l    = tid & 63;
  const int wv   = tid >> 6;
  const int c    = l & 15, quad = l >> 4;
  const int m0   = blockIdx.y * 128, n0 = blockIdx.x * 128;
  const int wm   = wv & 1, wn = wv >> 1;
  __shared__ _Float16 sA[128 * 64];
  __shared__ _Float16 sB[128 * 64];

  const _Float16* gA[4]; const _Float16* gB[4];
#pragma unroll
  for (int p = 0; p < 4; ++p) {
    int s = tid + p * 256, r = s >> 3, g = (s & 7) ^ (r & 7);
    gA[p] = A + (size_t)(m0 + r) * DM + g * 8;
    gB[p] = W + (size_t)(n0 + r) * DM + g * 8;
  }
  const int cx = c & 7;

  f32x4 acc[4][4] = {};
  for (int k0 = 0; k0 < DM; k0 += 64) {
    __syncthreads();
#pragma unroll
    for (int p = 0; p < 4; ++p) {
      gld16(gA[p] + k0, sA + (tid + p * 256) * 8);
      gld16(gB[p] + k0, sB + (tid + p * 256) * 8);
    }
    __syncthreads();
#pragma unroll
    for (int ks = 0; ks < 2; ++ks) {
      f16x8 af[4], bf[4];
#pragma unroll
      for (int i = 0; i < 4; ++i)
        af[i] = *(const f16x8*)&sA[(wm * 64 + i * 16 + c) * 64 + ((ks * 4 + quad) ^ cx) * 8];
#pragma unroll
      for (int j = 0; j < 4; ++j)
        bf[j] = *(const f16x8*)&sB[(wn * 64 + j * 16 + c) * 64 + ((ks * 4 + quad) ^ cx) * 8];
#pragma unroll
      for (int i = 0; i < 4; ++i)
#pragma unroll
        for (int j = 0; j < 4; ++j)
          acc[i][j] = __builtin_amdgcn_mfma_f32_16x16x32_f16(af[i], bf[j], acc[i][j], 0, 0, 0);
    }
  }
  if constexpr (VT) {
    // Vt[(b*16+h)*64 + dd][s]; acc rows (r) are consecutive s -> f16x4 stores
#pragma unroll
    for (int j = 0; j < 4; ++j) {
      int col = n0 + wn * 64 + j * 16 + c;
      float bb = bias[col];
      int hh = col >> 6, dd = col & 63;
#pragma unroll
      for (int i = 0; i < 4; ++i) {
        int row = m0 + wm * 64 + i * 16 + quad * 4;
        int bb2 = row >> 11, ss = row & (S_LEN - 1);
        _Float16* dst = (_Float16*)out + ((size_t)(bb2 * NH + hh) * DKH + dd) * S_LEN + ss;
        f16x4 v4;
#pragma unroll
        for (int r = 0; r < 4; ++r) v4[r] = (_Float16)((acc[i][j][r] + bb) * oscale);
        *(f16x4*)dst = v4;
      }
    }
  } else {
#pragma unroll
    for (int j = 0; j < 4; ++j) {
      int col = n0 + wn * 64 + j * 16 + c;
      float bb = bias[col];
#pragma unroll
      for (int i = 0; i < 4; ++i) {
        int row = m0 + wm * 64 + i * 16 + quad * 4;
#pragma unroll
        for (int r = 0; r < 4; ++r) {
          float vv = (acc[i][j][r] + bb) * oscale;
          out[(size_t)(row + r) * DM + col] = (OUT_T)vv;
        }
      }
    }
  }
}

#define SC_Q (0.125f * 1.44269504088896340736f)   // 1/sqrt(64) * log2(e)

__global__ __launch_bounds__(256) void proj3(
    const _Float16* __restrict__ xq, const _Float16* __restrict__ xk,
    const _Float16* __restrict__ xv, const _Float16* __restrict__ w16,
    const float* __restrict__ bq, const float* __restrict__ bk, const float* __restrict__ bv,
    _Float16* __restrict__ Q, _Float16* __restrict__ K, _Float16* __restrict__ Vt)
{
  const int z = blockIdx.z;
  if (z == 2) {
    gemm_core<_Float16, true>(xv, w16 + (size_t)2 * DM * DM, bv, Vt, 1.0f);
  } else if (z == 0) {
    gemm_core<_Float16, false>(xq, w16, bq, Q, SC_Q);
  } else {
    gemm_core<_Float16, false>(xk, w16 + (size_t)DM * DM, bk, K, 1.0f);
  }
}

__global__ __launch_bounds__(256) void out_gemm(
    const _Float16* __restrict__ ctx, const _Float16* __restrict__ wo,
    const float* __restrict__ bo, float* __restrict__ out)
{
  gemm_core<float, false>(ctx, wo, bo, out, 1.0f);
}

// ---------------- fused flash attention ----------------
// grid (S/64, B*H), 4 waves. Fixed-shift softmax in exp2 domain (Q pre-scaled).
// S^T: wave w computes key-stripe [w*16,w*16+16) x all 64 q (qf in regs).
// PV: wave (wq,wd) computes q-range wq*32+32 x d-range wd*32+32.
#define APP 72
__global__ __launch_bounds__(256) void attn(
    const _Float16* __restrict__ Q, const _Float16* __restrict__ K,
    const _Float16* __restrict__ Vt, _Float16* __restrict__ ctx)
{
  const int tid = threadIdx.x;
  const int l   = tid & 63, wv = tid >> 6;
  const int c   = l & 15, quad = l >> 4;
  const int q0  = blockIdx.x * 64;
  const int bh  = blockIdx.y;
  const int b   = bh >> 4, h = bh & 15;
  const int wq  = wv & 1, wd = wv >> 1;
  __shared__ _Float16 sK[64 * 64];     // [key][d], swizzled 16B blocks
  __shared__ _Float16 sV[64 * 64];     // [d][key], swizzled 16B blocks
  __shared__ _Float16 sP[64 * APP];    // shared P[q][key]
  __shared__ float    lsum[64][4];     // per-q, per-key-stripe partial sums

  // persistent Q fragments: qf[nt][ks] covers all 64 q rows of this block
  f16x8 qf[4][2];
#pragma unroll
  for (int nt = 0; nt < 4; ++nt) {
    const _Float16* Qg = Q + ((size_t)(b * S_LEN + q0 + nt * 16 + c)) * DM + h * DKH;
    qf[nt][0] = *(const f16x8*)(Qg + quad * 8);
    qf[nt][1] = *(const f16x8*)(Qg + 32 + quad * 8);
  }

  f32x4 o[2][2] = {};
  float l_part[4] = {};

  const _Float16* Kg0 = K + ((size_t)b * S_LEN) * DM + h * DKH;
  const _Float16* Vg0 = Vt + ((size_t)bh * DKH) * S_LEN;

  const int sa = tid,       ra = sa >> 3, ba = (sa & 7) ^ (ra & 7);
  const int sb = tid + 256, rb = sb >> 3, bb = (sb & 7) ^ (rb & 7);
  const _Float16* gKa = Kg0 + (size_t)ra * DM + ba * 8;
  const _Float16* gKb = Kg0 + (size_t)rb * DM + bb * 8;
  const _Float16* gVa = Vg0 + (size_t)ra * S_LEN + ba * 8;
  const _Float16* gVb = Vg0 + (size_t)rb * S_LEN + bb * 8;
  const int cx = c & 7;

  for (int kt = 0; kt < S_LEN / 64; ++kt) {
    const int k0 = kt * 64;
    __syncthreads();   // prior iter's sK/sV/sP reads complete
    gld16(gKa + (size_t)k0 * DM, sK + sa * 8);
    gld16(gKb + (size_t)k0 * DM, sK + sb * 8);
    gld16(gVa + k0,              sV + sa * 8);
    gld16(gVb + k0,              sV + sb * 8);
    __syncthreads();   // tiles ready (vmcnt drained here)

    // S^T stripe: keys wv*16..+16 (A=kf), all 64 q (B=qf, in regs)
    f32x4 sAcc[4] = {};
#pragma unroll
    for (int ks = 0; ks < 2; ++ks) {
      f16x8 kf = *(const f16x8*)&sK[(wv * 16 + c) * 64 + ((ks * 4 + quad) ^ cx) * 8];
#pragma unroll
      for (int nt = 0; nt < 4; ++nt)
        sAcc[nt] = __builtin_amdgcn_mfma_f32_16x16x32_f16(kf, qf[nt][ks], sAcc[nt], 0, 0, 0);
    }

    // P = 2^S; lane owns q=nt*16+c, keys wv*16+quad*4+{0..3}
#pragma unroll
    for (int nt = 0; nt < 4; ++nt) {
      float p0 = fast_exp2(sAcc[nt][0]);
      float p1 = fast_exp2(sAcc[nt][1]);
      float p2 = fast_exp2(sAcc[nt][2]);
      float p3 = fast_exp2(sAcc[nt][3]);
      l_part[nt] += (p0 + p1) + (p2 + p3);
      f16x2 lo = pk_f16(p0, p1);
      f16x2 hi = pk_f16(p2, p3);
      f16x4 pk; pk[0] = lo[0]; pk[1] = lo[1]; pk[2] = hi[0]; pk[3] = hi[1];
      *(f16x4*)&sP[(nt * 16 + c) * APP + wv * 16 + quad * 4] = pk;
    }
    __syncthreads();   // sP complete across waves

    // PV: wave covers q [wq*32,+32) x d [wd*32,+32)
#pragma unroll
    for (int ks = 0; ks < 2; ++ks) {
      f16x8 af[2], bf[2];
#pragma unroll
      for (int qb = 0; qb < 2; ++qb)
        af[qb] = *(const f16x8*)&sP[(wq * 32 + qb * 16 + c) * APP + ks * 32 + quad * 8];
#pragma unroll
      for (int db = 0; db < 2; ++db)
        bf[db] = *(const f16x8*)&sV[(wd * 32 + db * 16 + c) * 64 + ((ks * 4 + quad) ^ cx) * 8];
#pragma unroll
      for (int qb = 0; qb < 2; ++qb)
#pragma unroll
        for (int db = 0; db < 2; ++db)
          o[qb][db] = __builtin_amdgcn_mfma_f32_16x16x32_f16(af[qb], bf[db], o[qb][db], 0, 0, 0);
    }
  }

  // row sums: reduce each wave's stripe over its quads, then across waves via LDS
#pragma unroll
  for (int nt = 0; nt < 4; ++nt) {
    float s = l_part[nt];
    s += __shfl_xor(s, 16);
    s += __shfl_xor(s, 32);
    l_part[nt] = s;
  }
  if (quad == 0) {
#pragma unroll
    for (int nt = 0; nt < 4; ++nt) lsum[nt * 16 + c][wv] = l_part[nt];
  }
  __syncthreads();

  // store: lane holds o[qb][db][r] -> q = wq*32+qb*16+quad*4+r, d = wd*32+db*16+c
#pragma unroll
  for (int qb = 0; qb < 2; ++qb) {
#pragma unroll
    for (int r = 0; r < 4; ++r) {
      int q = wq * 32 + qb * 16 + quad * 4 + r;
      f32x4 ls = *(const f32x4*)&lsum[q][0];
      float inv = 1.0f / (ls[0] + ls[1] + ls[2] + ls[3]);
      _Float16* Og = ctx + ((size_t)(b * S_LEN + q0 + q)) * DM + h * DKH;
#pragma unroll
      for (int db = 0; db < 2; ++db)
        Og[wd * 32 + db * 16 + c] = (_Float16)(o[qb][db][r] * inv);
    }
  }
}

extern "C" void kernel_launch(void* const* d_in, const int* in_sizes, int n_in,
                              void* d_out, int out_size, void* d_ws, size_t ws_size,
                              hipStream_t stream)
{
  (void)in_sizes; (void)n_in; (void)out_size; (void)ws_size;
  const float* q  = (const float*)d_in[0];
  const float* k  = (const float*)d_in[1];
  const float* v  = (const float*)d_in[2];
  const float* wq = (const float*)d_in[3];
  const float* bq = (const float*)d_in[4];
  const float* wk = (const float*)d_in[5];
  const float* bk = (const float*)d_in[6];
  const float* wv = (const float*)d_in[7];
  const float* bv = (const float*)d_in[8];
  const float* wo = (const float*)d_in[9];
  const float* bo = (const float*)d_in[10];

  char* ws = (char*)d_ws;
  _Float16* XQ  = (_Float16*)(ws);                    // dead after proj3 -> CTX
  _Float16* XK  = (_Float16*)(ws + (8u  << 20));
  _Float16* XV  = (_Float16*)(ws + (16u << 20));
  _Float16* W16 = (_Float16*)(ws + (24u << 20));      // Wq,Wk,Wv,Wo
  _Float16* Qp  = (_Float16*)(ws + (32u << 20));
  _Float16* Kp  = (_Float16*)(ws + (40u << 20));
  _Float16* VT  = (_Float16*)(ws + (48u << 20));      // proj3 writes transposed V here
  _Float16* CTX = XQ;
  float* out = (float*)d_out;

  cvt_all<<<dim3(4096, 7), 256, 0, stream>>>(q, k, v, wq, wk, wv, wo, XQ, XK, XV, W16);
  proj3<<<dim3(8, 32, 3), 256, 0, stream>>>(XQ, XK, XV, W16, bq, bk, bv, Qp, Kp, VT);
  attn<<<dim3(32, 32), 256, 0, stream>>>(Qp, Kp, VT, CTX);
  out_gemm<<<dim3(8, 32), 256, 0, stream>>>(CTX, W16 + (size_t)3 * DM * DM, bo, out);
}

// Round 7
// 234.335 us; speedup vs baseline: 1.0736x; 1.0244x over previous
//
#include <hip/hip_runtime.h>

// MHA: B=2, S=2048, D=1024, H=16, DK=64. All GEMMs are x @ W.T (+bias).
// R7 changes (attn only; R6 split kept: S^T key-split w/ persistent qf, PV qxd):
//  - K/V double-buffered in LDS: prefetch tile kt+1 at top of iter kt ->
//    global latency hidden behind a full iteration of compute.
//  - barriers 3 -> 2 per iter (sP-ready + swap/drain).
//  - LDS = exactly 40KB (sP pitch 64 + 16B-block XOR swizzle; lsum aliased
//    onto dead sK) -> 4 blocks/CU co-resident WITH dbuf.
//  - v_dot2_f32_f16 row-sum accumulation; packed b64 sP stores kept.

#define S_LEN 2048
#define BATCH 2
#define DM    1024
#define NH    16
#define DKH   64
#define BS    (BATCH * S_LEN)   // 4096 rows

typedef _Float16 f16x8 __attribute__((ext_vector_type(8)));
typedef _Float16 f16x4 __attribute__((ext_vector_type(4)));
typedef _Float16 f16x2 __attribute__((ext_vector_type(2)));
typedef __fp16   h16x2 __attribute__((ext_vector_type(2)));
typedef float    f32x4 __attribute__((ext_vector_type(4)));

__device__ __forceinline__ f16x2 pk_f16(float a, float b) {
  h16x2 r = __builtin_amdgcn_cvt_pkrtz(a, b);
  return __builtin_bit_cast(f16x2, r);
}

__device__ __forceinline__ void gld16(const void* g, void* l) {
  __builtin_amdgcn_global_load_lds(
      (const __attribute__((address_space(1))) void*)g,
      (__attribute__((address_space(3))) void*)l, 16, 0, 0);
}

__device__ __forceinline__ float fast_exp2(float x) {
#if __has_builtin(__builtin_amdgcn_exp2f)
  return __builtin_amdgcn_exp2f(x);
#else
  return exp2f(x);
#endif
}

// ---------------- fp32 -> fp16 conversion ----------------
__global__ __launch_bounds__(256) void cvt_all(
    const float* __restrict__ q, const float* __restrict__ k, const float* __restrict__ v,
    const float* __restrict__ wq, const float* __restrict__ wk,
    const float* __restrict__ wv, const float* __restrict__ wo,
    _Float16* __restrict__ xq, _Float16* __restrict__ xk, _Float16* __restrict__ xv,
    _Float16* __restrict__ w16)
{
  const int y = blockIdx.y;
  const float* src; _Float16* dst; int n;
  if (y == 0)      { src = q;  dst = xq; n = BS * DM; }
  else if (y == 1) { src = k;  dst = xk; n = BS * DM; }
  else if (y == 2) { src = v;  dst = xv; n = BS * DM; }
  else {
    src = (y == 3) ? wq : ((y == 4) ? wk : ((y == 5) ? wv : wo));
    dst = w16 + (size_t)(y - 3) * (DM * DM);
    n = DM * DM;
  }
  int i0 = (blockIdx.x * 256 + threadIdx.x) * 4;
  if (i0 < n) {
    float4 f = *(const float4*)(src + i0);
    f16x2 lo = pk_f16(f.x, f.y);
    f16x2 hi = pk_f16(f.z, f.w);
    f16x4 h; h[0] = lo[0]; h[1] = lo[1]; h[2] = hi[0]; h[3] = hi[1];
    *(f16x4*)(dst + i0) = h;
  }
}

// ---------------- 128x128-tile GEMM: C = (A @ W^T + bias)*oscale ----------------
// BK=64, 16x16x32 MFMA, 4x4 frags/wave. global_load_lds staging, XOR swizzle.
// VT mode: write transposed into Vt[(b,h,d), s] with contiguous f16x4 stores.
template <typename OUT_T, bool VT>
__device__ __forceinline__ void gemm_core(
    const _Float16* __restrict__ A, const _Float16* __restrict__ W,
    const float* __restrict__ bias, OUT_T* __restrict__ out, float oscale)
{
  const int tid  = threadIdx.x;
  const int l    = tid & 63;
  const int wv   = tid >> 6;
  const int c    = l & 15, quad = l >> 4;
  const int m0   = blockIdx.y * 128, n0 = blockIdx.x * 128;
  const int wm   = wv & 1, wn = wv >> 1;
  __shared__ _Float16 sA[128 * 64];
  __shared__ _Float16 sB[128 * 64];

  const _Float16* gA[4]; const _Float16* gB[4];
#pragma unroll
  for (int p = 0; p < 4; ++p) {
    int s = tid + p * 256, r = s >> 3, g = (s & 7) ^ (r & 7);
    gA[p] = A + (size_t)(m0 + r) * DM + g * 8;
    gB[p] = W + (size_t)(n0 + r) * DM + g * 8;
  }
  const int cx = c & 7;

  f32x4 acc[4][4] = {};
  for (int k0 = 0; k0 < DM; k0 += 64) {
    __syncthreads();
#pragma unroll
    for (int p = 0; p < 4; ++p) {
      gld16(gA[p] + k0, sA + (tid + p * 256) * 8);
      gld16(gB[p] + k0, sB + (tid + p * 256) * 8);
    }
    __syncthreads();
#pragma unroll
    for (int ks = 0; ks < 2; ++ks) {
      f16x8 af[4], bf[4];
#pragma unroll
      for (int i = 0; i < 4; ++i)
        af[i] = *(const f16x8*)&sA[(wm * 64 + i * 16 + c) * 64 + ((ks * 4 + quad) ^ cx) * 8];
#pragma unroll
      for (int j = 0; j < 4; ++j)
        bf[j] = *(const f16x8*)&sB[(wn * 64 + j * 16 + c) * 64 + ((ks * 4 + quad) ^ cx) * 8];
#pragma unroll
      for (int i = 0; i < 4; ++i)
#pragma unroll
        for (int j = 0; j < 4; ++j)
          acc[i][j] = __builtin_amdgcn_mfma_f32_16x16x32_f16(af[i], bf[j], acc[i][j], 0, 0, 0);
    }
  }
  if constexpr (VT) {
#pragma unroll
    for (int j = 0; j < 4; ++j) {
      int col = n0 + wn * 64 + j * 16 + c;
      float bb = bias[col];
      int hh = col >> 6, dd = col & 63;
#pragma unroll
      for (int i = 0; i < 4; ++i) {
        int row = m0 + wm * 64 + i * 16 + quad * 4;
        int bb2 = row >> 11, ss = row & (S_LEN - 1);
        _Float16* dst = (_Float16*)out + ((size_t)(bb2 * NH + hh) * DKH + dd) * S_LEN + ss;
        f16x4 v4;
#pragma unroll
        for (int r = 0; r < 4; ++r) v4[r] = (_Float16)((acc[i][j][r] + bb) * oscale);
        *(f16x4*)dst = v4;
      }
    }
  } else {
#pragma unroll
    for (int j = 0; j < 4; ++j) {
      int col = n0 + wn * 64 + j * 16 + c;
      float bb = bias[col];
#pragma unroll
      for (int i = 0; i < 4; ++i) {
        int row = m0 + wm * 64 + i * 16 + quad * 4;
#pragma unroll
        for (int r = 0; r < 4; ++r) {
          float vv = (acc[i][j][r] + bb) * oscale;
          out[(size_t)(row + r) * DM + col] = (OUT_T)vv;
        }
      }
    }
  }
}

#define SC_Q (0.125f * 1.44269504088896340736f)   // 1/sqrt(64) * log2(e)

__global__ __launch_bounds__(256) void proj3(
    const _Float16* __restrict__ xq, const _Float16* __restrict__ xk,
    const _Float16* __restrict__ xv, const _Float16* __restrict__ w16,
    const float* __restrict__ bq, const float* __restrict__ bk, const float* __restrict__ bv,
    _Float16* __restrict__ Q, _Float16* __restrict__ K, _Float16* __restrict__ Vt)
{
  const int z = blockIdx.z;
  if (z == 2) {
    gemm_core<_Float16, true>(xv, w16 + (size_t)2 * DM * DM, bv, Vt, 1.0f);
  } else if (z == 0) {
    gemm_core<_Float16, false>(xq, w16, bq, Q, SC_Q);
  } else {
    gemm_core<_Float16, false>(xk, w16 + (size_t)DM * DM, bk, K, 1.0f);
  }
}

__global__ __launch_bounds__(256) void out_gemm(
    const _Float16* __restrict__ ctx, const _Float16* __restrict__ wo,
    const float* __restrict__ bo, float* __restrict__ out)
{
  gemm_core<float, false>(ctx, wo, bo, out, 1.0f);
}

// ---------------- fused flash attention (dbuf K/V, 2 barriers/iter) ----------------
// grid (S/64, B*H), 4 waves. Fixed-shift softmax in exp2 domain (Q pre-scaled).
// S^T: wave w computes key-stripe [w*16,+16) x all 64 q (qf persistent in regs).
// PV: wave (wq,wd) computes q [wq*32,+32) x d [wd*32,+32).
// sP: pitch 64, 16B-block swizzle phys=logical^(row&7). LDS total 40960 B.
__global__ __launch_bounds__(256, 4) void attn(
    const _Float16* __restrict__ Q, const _Float16* __restrict__ K,
    const _Float16* __restrict__ Vt, _Float16* __restrict__ ctx)
{
  const int tid = threadIdx.x;
  const int l   = tid & 63, wv = tid >> 6;
  const int c   = l & 15, quad = l >> 4;
  const int q0  = blockIdx.x * 64;
  const int bh  = blockIdx.y;
  const int b   = bh >> 4, h = bh & 15;
  const int wq  = wv & 1, wd = wv >> 1;
  __shared__ _Float16 sK[2][64 * 64];   // [key][d], swizzled 16B blocks
  __shared__ _Float16 sV[2][64 * 64];   // [d][key], swizzled 16B blocks
  __shared__ _Float16 sP[64 * 64];      // P[q][key], swizzled 16B blocks

  // persistent Q fragments covering all 64 q rows of this block
  f16x8 qf[4][2];
#pragma unroll
  for (int nt = 0; nt < 4; ++nt) {
    const _Float16* Qg = Q + ((size_t)(b * S_LEN + q0 + nt * 16 + c)) * DM + h * DKH;
    qf[nt][0] = *(const f16x8*)(Qg + quad * 8);
    qf[nt][1] = *(const f16x8*)(Qg + 32 + quad * 8);
  }

  f32x4 o[2][2] = {};
  float l_part[4] = {};
  const f16x2 ones = {(_Float16)1.0f, (_Float16)1.0f};

  const _Float16* Kg0 = K + ((size_t)b * S_LEN) * DM + h * DKH;
  const _Float16* Vg0 = Vt + ((size_t)bh * DKH) * S_LEN;

  const int sa = tid,       ra = sa >> 3, ba = (sa & 7) ^ (ra & 7);
  const int sb = tid + 256, rb = sb >> 3, bb = (sb & 7) ^ (rb & 7);
  const _Float16* gKa = Kg0 + (size_t)ra * DM + ba * 8;
  const _Float16* gKb = Kg0 + (size_t)rb * DM + bb * 8;
  const _Float16* gVa = Vg0 + (size_t)ra * S_LEN + ba * 8;
  const _Float16* gVb = Vg0 + (size_t)rb * S_LEN + bb * 8;
  const int cx = c & 7;

  // prefetch tile 0 -> buffer 0
  gld16(gKa, sK[0] + sa * 8);
  gld16(gKb, sK[0] + sb * 8);
  gld16(gVa, sV[0] + sa * 8);
  gld16(gVb, sV[0] + sb * 8);
  __syncthreads();

  for (int kt = 0; kt < S_LEN / 64; ++kt) {
    const int cur = kt & 1;
    // prefetch next tile into alternate buffer (latency hidden by this iter)
    const int nk = (kt < S_LEN / 64 - 1) ? (kt + 1) : kt;
    const size_t k0n = (size_t)nk * 64;
    gld16(gKa + k0n * DM, sK[cur ^ 1] + sa * 8);
    gld16(gKb + k0n * DM, sK[cur ^ 1] + sb * 8);
    gld16(gVa + k0n,      sV[cur ^ 1] + sa * 8);
    gld16(gVb + k0n,      sV[cur ^ 1] + sb * 8);

    // S^T stripe: keys wv*16..+16 (A=kf), all 64 q (B=qf in regs)
    f32x4 sAcc[4] = {};
#pragma unroll
    for (int ks = 0; ks < 2; ++ks) {
      f16x8 kf = *(const f16x8*)&sK[cur][(wv * 16 + c) * 64 + ((ks * 4 + quad) ^ cx) * 8];
#pragma unroll
      for (int nt = 0; nt < 4; ++nt)
        sAcc[nt] = __builtin_amdgcn_mfma_f32_16x16x32_f16(kf, qf[nt][ks], sAcc[nt], 0, 0, 0);
    }

    // P = 2^S; lane owns q=nt*16+c, keys wv*16+quad*4+{0..3}; packed b64 store
#pragma unroll
    for (int nt = 0; nt < 4; ++nt) {
      float p0 = fast_exp2(sAcc[nt][0]);
      float p1 = fast_exp2(sAcc[nt][1]);
      float p2 = fast_exp2(sAcc[nt][2]);
      float p3 = fast_exp2(sAcc[nt][3]);
      f16x2 lo = pk_f16(p0, p1);
      f16x2 hi = pk_f16(p2, p3);
      l_part[nt] = __builtin_amdgcn_fdot2(__builtin_bit_cast(h16x2, lo),
                                          __builtin_bit_cast(h16x2, ones), l_part[nt], false);
      l_part[nt] = __builtin_amdgcn_fdot2(__builtin_bit_cast(h16x2, hi),
                                          __builtin_bit_cast(h16x2, ones), l_part[nt], false);
      f16x4 pk; pk[0] = lo[0]; pk[1] = lo[1]; pk[2] = hi[0]; pk[3] = hi[1];
      int row = nt * 16 + c;
      int blk = (wv * 2 + (quad >> 1)) ^ (row & 7);   // logical 16B block ^ swizzle
      *(f16x4*)&sP[row * 64 + blk * 8 + (quad & 1) * 4] = pk;
    }
    __syncthreads();   // sP ready across waves

    // PV: wave covers q [wq*32,+32) x d [wd*32,+32)
#pragma unroll
    for (int ks = 0; ks < 2; ++ks) {
      f16x8 af[2], bf[2];
#pragma unroll
      for (int qb = 0; qb < 2; ++qb) {
        int row = wq * 32 + qb * 16 + c;
        af[qb] = *(const f16x8*)&sP[row * 64 + ((ks * 4 + quad) ^ (row & 7)) * 8];
      }
#pragma unroll
      for (int db = 0; db < 2; ++db)
        bf[db] = *(const f16x8*)&sV[cur][(wd * 32 + db * 16 + c) * 64 + ((ks * 4 + quad) ^ cx) * 8];
#pragma unroll
      for (int qb = 0; qb < 2; ++qb)
#pragma unroll
        for (int db = 0; db < 2; ++db)
          o[qb][db] = __builtin_amdgcn_mfma_f32_16x16x32_f16(af[qb], bf[db], o[qb][db], 0, 0, 0);
    }
    __syncthreads();   // drains prefetch (vmcnt); protects sP + retiring buffers
  }

  // row sums: reduce wave's key-stripe over quads, combine across waves via LDS
#pragma unroll
  for (int nt = 0; nt < 4; ++nt) {
    float s = l_part[nt];
    s += __shfl_xor(s, 16);
    s += __shfl_xor(s, 32);
    l_part[nt] = s;
  }
  float* lsum = (float*)&sK[0][0];   // alias dead sK: [64][4]
  if (quad == 0) {
#pragma unroll
    for (int nt = 0; nt < 4; ++nt) lsum[(nt * 16 + c) * 4 + wv] = l_part[nt];
  }
  __syncthreads();

  // store: lane holds o[qb][db][r] -> q = wq*32+qb*16+quad*4+r, d = wd*32+db*16+c
#pragma unroll
  for (int qb = 0; qb < 2; ++qb) {
#pragma unroll
    for (int r = 0; r < 4; ++r) {
      int q = wq * 32 + qb * 16 + quad * 4 + r;
      f32x4 ls = *(const f32x4*)&lsum[q * 4];
      float inv = 1.0f / (ls[0] + ls[1] + ls[2] + ls[3]);
      _Float16* Og = ctx + ((size_t)(b * S_LEN + q0 + q)) * DM + h * DKH;
#pragma unroll
      for (int db = 0; db < 2; ++db)
        Og[wd * 32 + db * 16 + c] = (_Float16)(o[qb][db][r] * inv);
    }
  }
}

extern "C" void kernel_launch(void* const* d_in, const int* in_sizes, int n_in,
                              void* d_out, int out_size, void* d_ws, size_t ws_size,
                              hipStream_t stream)
{
  (void)in_sizes; (void)n_in; (void)out_size; (void)ws_size;
  const float* q  = (const float*)d_in[0];
  const float* k  = (const float*)d_in[1];
  const float* v  = (const float*)d_in[2];
  const float* wq = (const float*)d_in[3];
  const float* bq = (const float*)d_in[4];
  const float* wk = (const float*)d_in[5];
  const float* bk = (const float*)d_in[6];
  const float* wv = (const float*)d_in[7];
  const float* bv = (const float*)d_in[8];
  const float* wo = (const float*)d_in[9];
  const float* bo = (const float*)d_in[10];

  char* ws = (char*)d_ws;
  _Float16* XQ  = (_Float16*)(ws);                    // dead after proj3 -> CTX
  _Float16* XK  = (_Float16*)(ws + (8u  << 20));
  _Float16* XV  = (_Float16*)(ws + (16u << 20));
  _Float16* W16 = (_Float16*)(ws + (24u << 20));      // Wq,Wk,Wv,Wo
  _Float16* Qp  = (_Float16*)(ws + (32u << 20));
  _Float16* Kp  = (_Float16*)(ws + (40u << 20));
  _Float16* VT  = (_Float16*)(ws + (48u << 20));      // proj3 writes transposed V here
  _Float16* CTX = XQ;
  float* out = (float*)d_out;

  cvt_all<<<dim3(4096, 7), 256, 0, stream>>>(q, k, v, wq, wk, wv, wo, XQ, XK, XV, W16);
  proj3<<<dim3(8, 32, 3), 256, 0, stream>>>(XQ, XK, XV, W16, bq, bk, bv, Qp, Kp, VT);
  attn<<<dim3(32, 32), 256, 0, stream>>>(Qp, Kp, VT, CTX);
  out_gemm<<<dim3(8, 32), 256, 0, stream>>>(CTX, W16 + (size_t)3 * DM * DM, bo, out);
}

// Round 8
// 226.450 us; speedup vs baseline: 1.1110x; 1.0348x over previous
//
#include <hip/hip_runtime.h>

// MHA: B=2, S=2048, D=1024, H=16, DK=64. All GEMMs are x @ W.T (+bias).
// R8: attn rewritten around 32x32x16 MFMA + register-resident P:
//  - K rows staged with swap23 (bit2<->bit3) row permutation; PV sum over keys
//    is permutation-invariant, and with this permutation the S^T C-layout
//    (after exp2) IS the PV A-operand layout -> P never touches LDS.
//  - 1 barrier per K-tile iter (prefetch-drain + buffer-swap only).
//  - 128-q blocks (grid 512, 2/CU, 8 waves/CU = 2/SIMD), wave owns 32 q.
//  - DS per wave-iter: 16 b128 for 16 mfma32 (2x MACs/byte vs 16x16 shape).

#define S_LEN 2048
#define BATCH 2
#define DM    1024
#define NH    16
#define DKH   64
#define BS    (BATCH * S_LEN)   // 4096 rows

typedef _Float16 f16x8 __attribute__((ext_vector_type(8)));
typedef _Float16 f16x4 __attribute__((ext_vector_type(4)));
typedef _Float16 f16x2 __attribute__((ext_vector_type(2)));
typedef __fp16   h16x2 __attribute__((ext_vector_type(2)));
typedef float    f32x4 __attribute__((ext_vector_type(4)));
typedef float    f32x16 __attribute__((ext_vector_type(16)));

__device__ __forceinline__ f16x2 pk_f16(float a, float b) {
  h16x2 r = __builtin_amdgcn_cvt_pkrtz(a, b);
  return __builtin_bit_cast(f16x2, r);
}

__device__ __forceinline__ void gld16(const void* g, void* l) {
  __builtin_amdgcn_global_load_lds(
      (const __attribute__((address_space(1))) void*)g,
      (__attribute__((address_space(3))) void*)l, 16, 0, 0);
}

__device__ __forceinline__ float fast_exp2(float x) {
#if __has_builtin(__builtin_amdgcn_exp2f)
  return __builtin_amdgcn_exp2f(x);
#else
  return exp2f(x);
#endif
}

__device__ __forceinline__ int swap23(int x) {   // swap bits 2 and 3 (involution)
  return (x & ~12) | ((x & 4) << 1) | ((x & 8) >> 1);
}

// ---------------- fp32 -> fp16 conversion ----------------
__global__ __launch_bounds__(256) void cvt_all(
    const float* __restrict__ q, const float* __restrict__ k, const float* __restrict__ v,
    const float* __restrict__ wq, const float* __restrict__ wk,
    const float* __restrict__ wv, const float* __restrict__ wo,
    _Float16* __restrict__ xq, _Float16* __restrict__ xk, _Float16* __restrict__ xv,
    _Float16* __restrict__ w16)
{
  const int y = blockIdx.y;
  const float* src; _Float16* dst; int n;
  if (y == 0)      { src = q;  dst = xq; n = BS * DM; }
  else if (y == 1) { src = k;  dst = xk; n = BS * DM; }
  else if (y == 2) { src = v;  dst = xv; n = BS * DM; }
  else {
    src = (y == 3) ? wq : ((y == 4) ? wk : ((y == 5) ? wv : wo));
    dst = w16 + (size_t)(y - 3) * (DM * DM);
    n = DM * DM;
  }
  int i0 = (blockIdx.x * 256 + threadIdx.x) * 4;
  if (i0 < n) {
    float4 f = *(const float4*)(src + i0);
    f16x2 lo = pk_f16(f.x, f.y);
    f16x2 hi = pk_f16(f.z, f.w);
    f16x4 hh; hh[0] = lo[0]; hh[1] = lo[1]; hh[2] = hi[0]; hh[3] = hi[1];
    *(f16x4*)(dst + i0) = hh;
  }
}

// ---------------- 128x128-tile GEMM: C = (A @ W^T + bias)*oscale ----------------
template <typename OUT_T, bool VT>
__device__ __forceinline__ void gemm_core(
    const _Float16* __restrict__ A, const _Float16* __restrict__ W,
    const float* __restrict__ bias, OUT_T* __restrict__ out, float oscale)
{
  const int tid  = threadIdx.x;
  const int l    = tid & 63;
  const int wv   = tid >> 6;
  const int c    = l & 15, quad = l >> 4;
  const int m0   = blockIdx.y * 128, n0 = blockIdx.x * 128;
  const int wm   = wv & 1, wn = wv >> 1;
  __shared__ _Float16 sA[128 * 64];
  __shared__ _Float16 sB[128 * 64];

  const _Float16* gA[4]; const _Float16* gB[4];
#pragma unroll
  for (int p = 0; p < 4; ++p) {
    int s = tid + p * 256, r = s >> 3, g = (s & 7) ^ (r & 7);
    gA[p] = A + (size_t)(m0 + r) * DM + g * 8;
    gB[p] = W + (size_t)(n0 + r) * DM + g * 8;
  }
  const int cx = c & 7;

  f32x4 acc[4][4] = {};
  for (int k0 = 0; k0 < DM; k0 += 64) {
    __syncthreads();
#pragma unroll
    for (int p = 0; p < 4; ++p) {
      gld16(gA[p] + k0, sA + (tid + p * 256) * 8);
      gld16(gB[p] + k0, sB + (tid + p * 256) * 8);
    }
    __syncthreads();
#pragma unroll
    for (int ks = 0; ks < 2; ++ks) {
      f16x8 af[4], bf[4];
#pragma unroll
      for (int i = 0; i < 4; ++i)
        af[i] = *(const f16x8*)&sA[(wm * 64 + i * 16 + c) * 64 + ((ks * 4 + quad) ^ cx) * 8];
#pragma unroll
      for (int j = 0; j < 4; ++j)
        bf[j] = *(const f16x8*)&sB[(wn * 64 + j * 16 + c) * 64 + ((ks * 4 + quad) ^ cx) * 8];
#pragma unroll
      for (int i = 0; i < 4; ++i)
#pragma unroll
        for (int j = 0; j < 4; ++j)
          acc[i][j] = __builtin_amdgcn_mfma_f32_16x16x32_f16(af[i], bf[j], acc[i][j], 0, 0, 0);
    }
  }
  if constexpr (VT) {
#pragma unroll
    for (int j = 0; j < 4; ++j) {
      int col = n0 + wn * 64 + j * 16 + c;
      float bb = bias[col];
      int hh = col >> 6, dd = col & 63;
#pragma unroll
      for (int i = 0; i < 4; ++i) {
        int row = m0 + wm * 64 + i * 16 + quad * 4;
        int bb2 = row >> 11, ss = row & (S_LEN - 1);
        _Float16* dst = (_Float16*)out + ((size_t)(bb2 * NH + hh) * DKH + dd) * S_LEN + ss;
        f16x4 v4;
#pragma unroll
        for (int r = 0; r < 4; ++r) v4[r] = (_Float16)((acc[i][j][r] + bb) * oscale);
        *(f16x4*)dst = v4;
      }
    }
  } else {
#pragma unroll
    for (int j = 0; j < 4; ++j) {
      int col = n0 + wn * 64 + j * 16 + c;
      float bb = bias[col];
#pragma unroll
      for (int i = 0; i < 4; ++i) {
        int row = m0 + wm * 64 + i * 16 + quad * 4;
#pragma unroll
        for (int r = 0; r < 4; ++r) {
          float vv = (acc[i][j][r] + bb) * oscale;
          out[(size_t)(row + r) * DM + col] = (OUT_T)vv;
        }
      }
    }
  }
}

#define SC_Q (0.125f * 1.44269504088896340736f)   // 1/sqrt(64) * log2(e)

__global__ __launch_bounds__(256) void proj3(
    const _Float16* __restrict__ xq, const _Float16* __restrict__ xk,
    const _Float16* __restrict__ xv, const _Float16* __restrict__ w16,
    const float* __restrict__ bq, const float* __restrict__ bk, const float* __restrict__ bv,
    _Float16* __restrict__ Q, _Float16* __restrict__ K, _Float16* __restrict__ Vt)
{
  const int z = blockIdx.z;
  if (z == 2) {
    gemm_core<_Float16, true>(xv, w16 + (size_t)2 * DM * DM, bv, Vt, 1.0f);
  } else if (z == 0) {
    gemm_core<_Float16, false>(xq, w16, bq, Q, SC_Q);
  } else {
    gemm_core<_Float16, false>(xk, w16 + (size_t)DM * DM, bk, K, 1.0f);
  }
}

__global__ __launch_bounds__(256) void out_gemm(
    const _Float16* __restrict__ ctx, const _Float16* __restrict__ wo,
    const float* __restrict__ bo, float* __restrict__ out)
{
  gemm_core<float, false>(ctx, wo, bo, out, 1.0f);
}

// ---------------- fused flash attention (32x32 MFMA, register-resident P) -----
// grid (S/128, B*H), 4 waves; wave owns 32 q-rows. Q pre-scaled so P = 2^S.
// K rows staged with swap23 row permutation; V natural. S^T C-layout -> exp2 ->
// direct PV A-operand (register renaming only). 1 barrier/iter. LDS 32 KB.
__global__ __launch_bounds__(256, 2) void attn(
    const _Float16* __restrict__ Q, const _Float16* __restrict__ K,
    const _Float16* __restrict__ Vt, _Float16* __restrict__ ctx)
{
  const int tid = threadIdx.x;
  const int l   = tid & 63, wv = tid >> 6;
  const int lo5 = l & 31, hf = l >> 5;
  const int q0  = blockIdx.x * 128;
  const int bh  = blockIdx.y;
  const int b   = bh >> 4, hd = bh & 15;
  __shared__ _Float16 sK[2][64 * 64];   // [slot-row][d], swizzled 16B blocks, rows permuted by swap23
  __shared__ _Float16 sV[2][64 * 64];   // [d][key], swizzled 16B blocks, natural

  // persistent Q B-frags: qf[kc] = Q[q = q0+wv*32+lo5][d = 16*kc + 8*hf .. +8]
  f16x8 qf[4];
  {
    const _Float16* Qg = Q + ((size_t)(b * S_LEN + q0 + wv * 32 + lo5)) * DM + hd * DKH + 8 * hf;
#pragma unroll
    for (int kc = 0; kc < 4; ++kc) qf[kc] = *(const f16x8*)(Qg + 16 * kc);
  }

  f32x16 o[2] = {};
  float l_part = 0.f;
  const f16x2 ones = {(_Float16)1.0f, (_Float16)1.0f};

  const _Float16* Kg0 = K + ((size_t)b * S_LEN) * DM + hd * DKH;
  const _Float16* Vg0 = Vt + ((size_t)bh * DKH) * S_LEN;

  // staging: 512 16B slots per tile per array; thread handles slots {tid, tid+256}.
  // slot s: LDS block s (linear); row r=s>>3; global block (s&7)^(r&7).
  // K global row = swap23(r) (row permutation); V rows are d (natural).
  const int sa = tid,       ra = sa >> 3, ba = (sa & 7) ^ (ra & 7);
  const int sb = tid + 256, rb = sb >> 3, bb = (sb & 7) ^ (rb & 7);
  const _Float16* gKa = Kg0 + (size_t)swap23(ra) * DM + ba * 8;
  const _Float16* gKb = Kg0 + (size_t)swap23(rb) * DM + bb * 8;
  const _Float16* gVa = Vg0 + (size_t)ra * S_LEN + ba * 8;
  const _Float16* gVb = Vg0 + (size_t)rb * S_LEN + bb * 8;
  const int rx = lo5 & 7;   // frag-read block xor (row & 7)

  // prefetch tile 0 -> buffer 0
  gld16(gKa, sK[0] + sa * 8);
  gld16(gKb, sK[0] + sb * 8);
  gld16(gVa, sV[0] + sa * 8);
  gld16(gVb, sV[0] + sb * 8);
  __syncthreads();

  for (int kt = 0; kt < S_LEN / 64; ++kt) {
    const int cur = kt & 1;
    const int nk = (kt < S_LEN / 64 - 1) ? (kt + 1) : kt;
    const size_t k0n = (size_t)nk * 64;
    gld16(gKa + k0n * DM, sK[cur ^ 1] + sa * 8);
    gld16(gKb + k0n * DM, sK[cur ^ 1] + sb * 8);
    gld16(gVa + k0n,      sV[cur ^ 1] + sa * 8);
    gld16(gVb + k0n,      sV[cur ^ 1] + sb * 8);

    // S^T: C[slot-row][q] for 2 key-32-blocks; A=kf (m=slot in kb), B=qf (n=q)
    f32x16 sAcc[2] = {};
#pragma unroll
    for (int kb = 0; kb < 2; ++kb)
#pragma unroll
      for (int kc = 0; kc < 4; ++kc) {
        f16x8 kf = *(const f16x8*)&sK[cur][(32 * kb + lo5) * 64 + ((2 * kc + hf) ^ rx) * 8];
        sAcc[kb] = __builtin_amdgcn_mfma_f32_32x32x16_f16(kf, qf[kc], sAcc[kb], 0, 0, 0);
      }

    // P = 2^S, packed to fp16 in C-reg order; pPv[kb][half] is directly the
    // PV A-operand for chunk kc2 = 2*kb + half (swap23 makes layouts coincide).
    f16x8 pPv[2][2];
#pragma unroll
    for (int kb = 0; kb < 2; ++kb)
#pragma unroll
      for (int half = 0; half < 2; ++half)
#pragma unroll
        for (int j2 = 0; j2 < 4; ++j2) {
          float p0 = fast_exp2(sAcc[kb][8 * half + 2 * j2]);
          float p1 = fast_exp2(sAcc[kb][8 * half + 2 * j2 + 1]);
          f16x2 pk = pk_f16(p0, p1);
          pPv[kb][half][2 * j2]     = pk[0];
          pPv[kb][half][2 * j2 + 1] = pk[1];
          l_part = __builtin_amdgcn_fdot2(__builtin_bit_cast(h16x2, pk),
                                          __builtin_bit_cast(h16x2, ones), l_part, false);
        }

    // PV: O[q][d] tiles for 2 d-32-blocks; A = pPv (regs!), B = vf from sV
#pragma unroll
    for (int db = 0; db < 2; ++db)
#pragma unroll
      for (int kc2 = 0; kc2 < 4; ++kc2) {
        f16x8 vf = *(const f16x8*)&sV[cur][(32 * db + lo5) * 64 + ((2 * kc2 + hf) ^ rx) * 8];
        o[db] = __builtin_amdgcn_mfma_f32_32x32x16_f16(pPv[kc2 >> 1][kc2 & 1], vf, o[db], 0, 0, 0);
      }

    __syncthreads();   // drains prefetch (vmcnt) + all waves done reading cur
  }

  // row sums: lane (lo5, hf) holds partial for q-row lo5; combine halves
  l_part += __shfl_xor(l_part, 32);
  float* lsum = (float*)&sK[0][0] + wv * 32;   // dead LDS; per-wave region
  if (hf == 0) lsum[lo5] = l_part;             // DS in-order within wave
  float inv[16];
#pragma unroll
  for (int r = 0; r < 16; ++r) {
    int qq = 8 * (r >> 2) + 4 * hf + (r & 3);
    inv[r] = 1.0f / lsum[qq];                  // broadcast reads (2 addrs/wave)
  }

  // store: o[db] C-layout: q = 8*(r>>2)+4*hf+(r&3), d = 32*db + lo5
  _Float16* Og = ctx + ((size_t)(b * S_LEN + q0 + wv * 32)) * DM + hd * DKH;
#pragma unroll
  for (int db = 0; db < 2; ++db)
#pragma unroll
    for (int r = 0; r < 16; ++r) {
      int qq = 8 * (r >> 2) + 4 * hf + (r & 3);
      Og[(size_t)qq * DM + 32 * db + lo5] = (_Float16)(o[db][r] * inv[r]);
    }
}

extern "C" void kernel_launch(void* const* d_in, const int* in_sizes, int n_in,
                              void* d_out, int out_size, void* d_ws, size_t ws_size,
                              hipStream_t stream)
{
  (void)in_sizes; (void)n_in; (void)out_size; (void)ws_size;
  const float* q  = (const float*)d_in[0];
  const float* k  = (const float*)d_in[1];
  const float* v  = (const float*)d_in[2];
  const float* wq = (const float*)d_in[3];
  const float* bq = (const float*)d_in[4];
  const float* wk = (const float*)d_in[5];
  const float* bk = (const float*)d_in[6];
  const float* wv = (const float*)d_in[7];
  const float* bv = (const float*)d_in[8];
  const float* wo = (const float*)d_in[9];
  const float* bo = (const float*)d_in[10];

  char* ws = (char*)d_ws;
  _Float16* XQ  = (_Float16*)(ws);                    // dead after proj3 -> CTX
  _Float16* XK  = (_Float16*)(ws + (8u  << 20));
  _Float16* XV  = (_Float16*)(ws + (16u << 20));
  _Float16* W16 = (_Float16*)(ws + (24u << 20));      // Wq,Wk,Wv,Wo
  _Float16* Qp  = (_Float16*)(ws + (32u << 20));
  _Float16* Kp  = (_Float16*)(ws + (40u << 20));
  _Float16* VT  = (_Float16*)(ws + (48u << 20));      // proj3 writes transposed V here
  _Float16* CTX = XQ;
  float* out = (float*)d_out;

  cvt_all<<<dim3(4096, 7), 256, 0, stream>>>(q, k, v, wq, wk, wv, wo, XQ, XK, XV, W16);
  proj3<<<dim3(8, 32, 3), 256, 0, stream>>>(XQ, XK, XV, W16, bq, bk, bv, Qp, Kp, VT);
  attn<<<dim3(16, 32), 256, 0, stream>>>(Qp, Kp, VT, CTX);
  out_gemm<<<dim3(8, 32), 256, 0, stream>>>(CTX, W16 + (size_t)3 * DM * DM, bo, out);
}